// Round 13
// baseline (173.009 us; speedup 1.0000x reference)
//
#include <hip/hip_runtime.h>

#define N_ATOMS 20000
#define BATCH   16
#define N_BONDS 60000
#define NB      (N_ATOMS * BATCH)      // 320000
#define CAP     32                     // max neighbors/node (deg~Poisson(6); P(>=32)~1e-16)

#define TRANS_BLOCKS 1250   // 1250*256 = 320000 = N*B
#define DEG_BLOCKS   235    // ceil(60000/256)
#define NGROUPS      1250   // node groups of 16

// Workspace (int-indexed):
//   cnt[20000] | done[1] | pad | Mc[12]f | adjF[20000*32] | posT[N][8] uint4 | h2T same
#define OFF_CNT   0
#define OFF_DONE  20000
#define OFF_MC    20008
#define OFF_ADJF  20024                       // byte 80096 %16==0 -> int4 OK
#define OFF_POST  (OFF_ADJF + N_ATOMS * CAP)  // 660024; byte %16==0 -> uint4 OK
#define OFF_H2T   (OFF_POST + NB * 2)         // 1300024

// f32 <-> bf16 (RNE; data has no NaN/Inf).
__device__ __forceinline__ unsigned short f2bf(float f) {
    unsigned int u = __float_as_uint(f);
    u += 0x7FFFu + ((u >> 16) & 1u);
    return (unsigned short)(u >> 16);
}
__device__ __forceinline__ float bflo(unsigned int u) { return __uint_as_float(u << 16); }
__device__ __forceinline__ float bfhi(unsigned int u) { return __uint_as_float(u & 0xFFFF0000u); }

// blocks [0,1250): transpose positions[B][N][3] -> posT[N][16] bf16x4 (b-fastest,
//                  128B-contiguous per node). blocks [1250,1485): slot fill.
// block 1485: Mc = [W_msg @ W_upd ; b_msg @ W_upd].
__global__ void build_kernel(const float* __restrict__ pos, const int* __restrict__ bonds,
                             const float* __restrict__ W_msg, const float* __restrict__ b_msg,
                             const float* __restrict__ W_upd,
                             int* __restrict__ cnt, int* __restrict__ adjF,
                             float* __restrict__ Mc, ushort4* __restrict__ posT) {
    int blk = blockIdx.x;
    if (blk < TRANS_BLOCKS) {
        int t = blk * 256 + threadIdx.x;        // 0..319999
        int b = t & 15, n = t >> 4;
        const float* p = pos + ((size_t)b * N_ATOMS + n) * 3;
        posT[n * 16 + b] = make_ushort4(f2bf(p[0]), f2bf(p[1]), f2bf(p[2]), 0);
    } else if (blk < TRANS_BLOCKS + DEG_BLOCKS) {
        int e = (blk - TRANS_BLOCKS) * 256 + threadIdx.x;
        if (e < N_BONDS) {
            int a0 = bonds[2 * e], a1 = bonds[2 * e + 1];
            int s0 = atomicAdd(&cnt[a0], 1);
            if (s0 < CAP) adjF[a0 * CAP + s0] = a1;
            int s1 = atomicAdd(&cnt[a1], 1);
            if (s1 < CAP) adjF[a1 * CAP + s1] = a0;
        }
    } else {
        int t = threadIdx.x;
        if (t < 12) {
            float s = 0.0f;
            if (t < 9) {
                int i = t / 3, j = t % 3;
                for (int k = 0; k < 128; ++k) s += W_msg[i * 128 + k] * W_upd[k * 3 + j];
            } else {
                int j = t - 9;
                for (int k = 0; k < 128; ++k) s += b_msg[k] * W_upd[k * 3 + j];
            }
            Mc[t] = s;
        }
    }
}

// Fused producer-consumer gather. Blocks [0,1250): iteration 1 (posT -> h2T),
// then agent-release increment of done. Blocks [1250,2500): prefetch adj,
// spin on done==1250 (relaxed + s_sleep), acquire, run iteration 2 -> out.
// 8 lanes/node x uint4 (2 batches/lane); 16 nodes per 128-thread block.
// __launch_bounds__(128,8): VGPR<=64 -> 16 blocks/CU -> all 2500 co-resident
// (deadlock-free regardless of dispatch order).
__global__ __launch_bounds__(128, 8)
void fused_gather_kernel(const uint4* __restrict__ posT, uint4* __restrict__ h2T,
                         const int* __restrict__ cnt, const int* __restrict__ adjF,
                         const float* __restrict__ Mc, const float* __restrict__ b_upd,
                         int* __restrict__ done, float* __restrict__ outP) {
    __shared__ float lds[16 * 51];           // consumer re-transpose (stride 51)
    int t = threadIdx.x;
    int l = t & 7;                           // lane within node-group: batches 2l,2l+1
    int nl = t >> 3;                         // 0..15
    bool producer = blockIdx.x < NGROUPS;
    int g = producer ? blockIdx.x : (blockIdx.x - NGROUPS);
    int n = g * 16 + nl;
    const int4* al4 = (const int4*)(adjF + n * CAP);
    int4 ja = al4[0];                        // always in-bounds (CAP=32); independent of h2T
    int4 jb = al4[1];
    // hoisted uniform transform loads (ready: build node completed)
    float m0 = Mc[0], m1 = Mc[1], m2 = Mc[2];
    float m3 = Mc[3], m4 = Mc[4], m5 = Mc[5];
    float m6 = Mc[6], m7 = Mc[7], m8 = Mc[8];
    float c0 = Mc[9], c1 = Mc[10], c2 = Mc[11];
    float bu0 = b_upd[0], bu1 = b_upd[1], bu2 = b_upd[2];

    int d;
    uint4 mh;
    const uint4* hT;
    if (producer) {
        hT = posT;
        int dc = cnt[n];                     // group-uniform broadcast
        d = dc > CAP ? CAP : dc;
        mh = hT[(size_t)n * 8 + l];
    } else {
        hT = h2T;
        // wait for all producers (single counter; t0 polls, block barriers)
        if (t == 0) {
            while (__hip_atomic_load(done, __ATOMIC_RELAXED, __HIP_MEMORY_SCOPE_AGENT) < NGROUPS)
                __builtin_amdgcn_s_sleep(8);
            (void)__hip_atomic_load(done, __ATOMIC_ACQUIRE, __HIP_MEMORY_SCOPE_AGENT);
        }
        __syncthreads();
        mh = hT[(size_t)n * 8 + l];
        d = (int)(mh.y >> 16);               // deg packed by producer
    }

    float ax = 0.f, ay = 0.f, az = 0.f;      // batch 2l
    float bx = 0.f, by = 0.f, bz = 0.f;      // batch 2l+1
#define ACC(J) { uint4 v = hT[(size_t)(J) * 8 + l]; \
                 ax += bflo(v.x); ay += bfhi(v.x); az += bflo(v.y); \
                 bx += bflo(v.z); by += bfhi(v.z); bz += bflo(v.w); }
    if (0 < d) ACC(ja.x)
    if (1 < d) ACC(ja.y)
    if (2 < d) ACC(ja.z)
    if (3 < d) ACC(ja.w)
    if (4 < d) ACC(jb.x)
    if (5 < d) ACC(jb.y)
    if (6 < d) ACC(jb.z)
    if (7 < d) ACC(jb.w)
    for (int k0 = 8; k0 < d; k0 += 8) {      // rare tail (P(d>8)~15%)
        ja = al4[k0 >> 2];
        jb = al4[(k0 >> 2) + 1];
        if (k0 + 0 < d) ACC(ja.x)
        if (k0 + 1 < d) ACC(ja.y)
        if (k0 + 2 < d) ACC(ja.z)
        if (k0 + 3 < d) ACC(ja.w)
        if (k0 + 4 < d) ACC(jb.x)
        if (k0 + 5 < d) ACC(jb.y)
        if (k0 + 6 < d) ACC(jb.z)
        if (k0 + 7 < d) ACC(jb.w)
    }
#undef ACC
    float inv = d > 0 ? 1.0f / (float)d : 0.0f;
    float flag = d > 0 ? 1.0f : 0.0f;
    float k0f = flag * c0 + bu0, k1f = flag * c1 + bu1, k2f = flag * c2 + bu2;
    float oa0 = bflo(mh.x) + inv * (ax * m0 + ay * m3 + az * m6) + k0f;
    float oa1 = bfhi(mh.x) + inv * (ax * m1 + ay * m4 + az * m7) + k1f;
    float oa2 = bflo(mh.y) + inv * (ax * m2 + ay * m5 + az * m8) + k2f;
    float ob0 = bflo(mh.z) + inv * (bx * m0 + by * m3 + bz * m6) + k0f;
    float ob1 = bfhi(mh.z) + inv * (bx * m1 + by * m4 + bz * m7) + k1f;
    float ob2 = bflo(mh.w) + inv * (bx * m2 + by * m5 + bz * m8) + k2f;

    if (producer) {
        unsigned int dw = (unsigned int)d << 16;
        uint4 o;
        o.x = (unsigned int)f2bf(oa0) | ((unsigned int)f2bf(oa1) << 16);
        o.y = (unsigned int)f2bf(oa2) | dw;
        o.z = (unsigned int)f2bf(ob0) | ((unsigned int)f2bf(ob1) << 16);
        o.w = (unsigned int)f2bf(ob2) | dw;
        h2T[(size_t)n * 8 + l] = o;
        __syncthreads();                     // all block stores issued
        if (t == 0)
            __hip_atomic_fetch_add(done, 1, __ATOMIC_RELEASE, __HIP_MEMORY_SCOPE_AGENT);
    } else {
        int b0 = 2 * l, b1 = 2 * l + 1;
        lds[nl * 51 + b0 * 3 + 0] = oa0;
        lds[nl * 51 + b0 * 3 + 1] = oa1;
        lds[nl * 51 + b0 * 3 + 2] = oa2;
        lds[nl * 51 + b1 * 3 + 0] = ob0;
        lds[nl * 51 + b1 * 3 + 1] = ob1;
        lds[nl * 51 + b1 * 3 + 2] = ob2;
        __syncthreads();
        int n2 = t & 15, q = t >> 4;         // q: batch pair 2q,2q+1; n2 fastest
        int gn = g * 16 + n2;
        float* op0 = outP + ((size_t)(2 * q) * N_ATOMS + gn) * 3;
        float* op1 = op0 + (size_t)N_ATOMS * 3;
        op0[0] = lds[n2 * 51 + (2 * q) * 3 + 0];
        op0[1] = lds[n2 * 51 + (2 * q) * 3 + 1];
        op0[2] = lds[n2 * 51 + (2 * q) * 3 + 2];
        op1[0] = lds[n2 * 51 + (2 * q + 1) * 3 + 0];
        op1[1] = lds[n2 * 51 + (2 * q + 1) * 3 + 1];
        op1[2] = lds[n2 * 51 + (2 * q + 1) * 3 + 2];
    }
}

extern "C" void kernel_launch(void* const* d_in, const int* in_sizes, int n_in,
                              void* d_out, int out_size, void* d_ws, size_t ws_size,
                              hipStream_t stream) {
    const float* positions = (const float*)d_in[0];
    const int* bonds = (const int*)d_in[1];
    const float* W_msg = (const float*)d_in[2];
    const float* b_msg = (const float*)d_in[3];
    const float* W_upd = (const float*)d_in[4];
    const float* b_upd = (const float*)d_in[5];
    float* out = (float*)d_out;

    int* wsi = (int*)d_ws;
    int* cnt = wsi + OFF_CNT;
    int* done = wsi + OFF_DONE;
    float* Mc = (float*)(wsi + OFF_MC);
    int* adjF = wsi + OFF_ADJF;
    ushort4* posT = (ushort4*)(wsi + OFF_POST);
    uint4* posT4 = (uint4*)(wsi + OFF_POST);
    uint4* h2T4 = (uint4*)(wsi + OFF_H2T);

    // 1. zero slot counters + done flag (single driver fill, capture-legal)
    hipMemsetAsync(cnt, 0, (N_ATOMS + 1) * sizeof(int), stream);
    // 2. transpose -> posT (bf16) || slot-fill adjacency || Mc (fused by block range)
    build_kernel<<<TRANS_BLOCKS + DEG_BLOCKS + 1, 256, 0, stream>>>(
        positions, bonds, W_msg, b_msg, W_upd, cnt, adjF, Mc, posT);
    // 3. fused: blocks 0-1249 iteration 1 -> h2T; blocks 1250-2499 spin, then
    //    iteration 2 -> out[B][N][3]
    fused_gather_kernel<<<2 * NGROUPS, 128, 0, stream>>>(
        posT4, h2T4, cnt, adjF, Mc, b_upd, done, out);
}

// Round 14
// 39.608 us; speedup vs baseline: 4.3680x; 4.3680x over previous
//
#include <hip/hip_runtime.h>

#define N_ATOMS 20000
#define BATCH   16
#define N_BONDS 60000
#define NB      (N_ATOMS * BATCH)      // 320000
#define CAP     32                     // max neighbors/node (deg~Poisson(6); P(>=32)~1e-16)

#define TILE_N       64                // nodes per transpose tile
#define TRANS_BLOCKS 313               // ceil(20000/64); last block handles 32 nodes
#define DEG_BLOCKS   235               // ceil(60000/256)
#define NGROUPS      1250              // node groups of 16 (gather)

// Workspace (int-indexed):
//   cnt[20000] | Mc[12]f(+pad) | adjF[20000*32] | posT[N][8] uint4 | h2T same
#define OFF_CNT   0
#define OFF_MC    20000
#define OFF_ADJF  20016                       // byte 80064 %16==0 -> int4 OK
#define OFF_POST  (OFF_ADJF + N_ATOMS * CAP)  // byte %16==0 -> uint4 OK
#define OFF_H2T   (OFF_POST + NB * 2)

// f32 <-> bf16 (RNE; data has no NaN/Inf).
__device__ __forceinline__ unsigned short f2bf(float f) {
    unsigned int u = __float_as_uint(f);
    u += 0x7FFFu + ((u >> 16) & 1u);
    return (unsigned short)(u >> 16);
}
__device__ __forceinline__ float bflo(unsigned int u) { return __uint_as_float(u << 16); }
__device__ __forceinline__ float bfhi(unsigned int u) { return __uint_as_float(u & 0xFFFF0000u); }

// blocks [0,313): LDS-tiled transpose positions[B][N][3] -> posT[N][16] bf16x4.
//   Phase 1: fully-coalesced float4 reads (192 contiguous floats per batch row).
//   Phase 2: coalesced 128B ushort4 row writes. LDS row padded to 193 floats
//   (bank-stride 1, conflict-free).
// blocks [313,548): per-edge slot fill via atomic cnt.
// block 548: Mc = [W_msg @ W_upd ; b_msg @ W_upd].
__global__ __launch_bounds__(256) void build_kernel(
        const float* __restrict__ pos, const int* __restrict__ bonds,
        const float* __restrict__ W_msg, const float* __restrict__ b_msg,
        const float* __restrict__ W_upd,
        int* __restrict__ cnt, int* __restrict__ adjF,
        float* __restrict__ Mc, ushort4* __restrict__ posT) {
    int blk = blockIdx.x;
    if (blk < TRANS_BLOCKS) {
        __shared__ float lds[16][193];          // [batch][node*3 + comp], padded
        int t = threadIdx.x;
        int n0 = blk * TILE_N;
        int nt = min(TILE_N, N_ATOMS - n0);     // 64, or 32 for the last block
        int nf4 = nt * 3 / 4;                   // float4s per batch row (48 or 24)
        // phase 1: coalesced reads
        for (int r = 0; r < 3; ++r) {
            int idx = r * 256 + t;              // 0..767
            int b = idx / 48, f = idx % 48;     // f: float4 index within row
            if (b < 16 && f < nf4) {
                const float4 v = *(const float4*)(pos + (size_t)b * (N_ATOMS * 3)
                                                  + (size_t)n0 * 3 + f * 4);
                lds[b][f * 4 + 0] = v.x;
                lds[b][f * 4 + 1] = v.y;
                lds[b][f * 4 + 2] = v.z;
                lds[b][f * 4 + 3] = v.w;
            }
        }
        __syncthreads();
        // phase 2: coalesced bf16 row writes (b fastest within 16-lane groups)
        for (int w = 0; w < 4; ++w) {
            int o = w * 256 + t;                // 0..1023
            int nloc = o >> 4, b = o & 15;
            if (nloc < nt) {
                posT[(size_t)(n0 + nloc) * 16 + b] =
                    make_ushort4(f2bf(lds[b][nloc * 3 + 0]),
                                 f2bf(lds[b][nloc * 3 + 1]),
                                 f2bf(lds[b][nloc * 3 + 2]), 0);
            }
        }
    } else if (blk < TRANS_BLOCKS + DEG_BLOCKS) {
        int e = (blk - TRANS_BLOCKS) * 256 + threadIdx.x;
        if (e < N_BONDS) {
            int a0 = bonds[2 * e], a1 = bonds[2 * e + 1];
            int s0 = atomicAdd(&cnt[a0], 1);
            if (s0 < CAP) adjF[a0 * CAP + s0] = a1;
            int s1 = atomicAdd(&cnt[a1], 1);
            if (s1 < CAP) adjF[a1 * CAP + s1] = a0;
        }
    } else {
        int t = threadIdx.x;
        if (t < 12) {
            float s = 0.0f;
            if (t < 9) {
                int i = t / 3, j = t % 3;
                for (int k = 0; k < 128; ++k) s += W_msg[i * 128 + k] * W_upd[k * 3 + j];
            } else {
                int j = t - 9;
                for (int k = 0; k < 128; ++k) s += b_msg[k] * W_upd[k * 3 + j];
            }
            Mc[t] = s;
        }
    }
}

// Node-major fused iteration, bf16 state, wide lanes: 8 lanes/node x uint4
// (2 batches/lane). Block = 16 nodes x 8 lanes = 128 threads. Front-loaded MLP:
// 2 unconditional int4 adj loads cover d<=8 (84%); predicated independent
// gathers. f32 accumulation.
// FINAL=false: d from cnt[n]; packs d into .w halves. FINAL=true: d from
// packed .w (no cnt load); LDS re-transpose to out[B][N][3].
template <bool FINAL>
__global__ __launch_bounds__(128) void gather_kernel(const uint4* __restrict__ hT,
                                                     const int* __restrict__ cnt,
                                                     const int* __restrict__ adjF,
                                                     const float* __restrict__ Mc,
                                                     const float* __restrict__ b_upd,
                                                     uint4* __restrict__ outT,
                                                     float* __restrict__ outP) {
    __shared__ float lds[16 * 51];           // stride 51: conflict-free re-transpose
    int t = threadIdx.x;
    int l = t & 7;                           // lane within node-group: batches 2l,2l+1
    int nl = t >> 3;                         // 0..15
    int n = blockIdx.x * 16 + nl;            // 1250*16 = 20000 exactly
    const int4* al4 = (const int4*)(adjF + n * CAP);
    int4 ja = al4[0];                        // always in-bounds (CAP=32)
    int4 jb = al4[1];
    uint4 mh = hT[(size_t)n * 8 + l];        // row n, 2 batches for this lane
    int d;
    if (FINAL) {
        d = (int)(mh.y >> 16);               // deg packed by gather<false>
    } else {
        int dc = cnt[n];                     // group-uniform broadcast
        d = dc > CAP ? CAP : dc;
    }
    float m0 = Mc[0], m1 = Mc[1], m2 = Mc[2];
    float m3 = Mc[3], m4 = Mc[4], m5 = Mc[5];
    float m6 = Mc[6], m7 = Mc[7], m8 = Mc[8];
    float c0 = Mc[9], c1 = Mc[10], c2 = Mc[11];
    float bu0 = b_upd[0], bu1 = b_upd[1], bu2 = b_upd[2];
    float ax = 0.f, ay = 0.f, az = 0.f;      // batch 2l
    float bx = 0.f, by = 0.f, bz = 0.f;      // batch 2l+1
#define ACC(J) { uint4 v = hT[(size_t)(J) * 8 + l]; \
                 ax += bflo(v.x); ay += bfhi(v.x); az += bflo(v.y); \
                 bx += bflo(v.z); by += bfhi(v.z); bz += bflo(v.w); }
    if (0 < d) ACC(ja.x)
    if (1 < d) ACC(ja.y)
    if (2 < d) ACC(ja.z)
    if (3 < d) ACC(ja.w)
    if (4 < d) ACC(jb.x)
    if (5 < d) ACC(jb.y)
    if (6 < d) ACC(jb.z)
    if (7 < d) ACC(jb.w)
    for (int k0 = 8; k0 < d; k0 += 8) {      // rare tail (P(d>8)~15%)
        ja = al4[k0 >> 2];
        jb = al4[(k0 >> 2) + 1];
        if (k0 + 0 < d) ACC(ja.x)
        if (k0 + 1 < d) ACC(ja.y)
        if (k0 + 2 < d) ACC(ja.z)
        if (k0 + 3 < d) ACC(ja.w)
        if (k0 + 4 < d) ACC(jb.x)
        if (k0 + 5 < d) ACC(jb.y)
        if (k0 + 6 < d) ACC(jb.z)
        if (k0 + 7 < d) ACC(jb.w)
    }
#undef ACC
    float inv = d > 0 ? 1.0f / (float)d : 0.0f;
    float flag = d > 0 ? 1.0f : 0.0f;
    float k0f = flag * c0 + bu0, k1f = flag * c1 + bu1, k2f = flag * c2 + bu2;
    float oa0 = bflo(mh.x) + inv * (ax * m0 + ay * m3 + az * m6) + k0f;
    float oa1 = bfhi(mh.x) + inv * (ax * m1 + ay * m4 + az * m7) + k1f;
    float oa2 = bflo(mh.y) + inv * (ax * m2 + ay * m5 + az * m8) + k2f;
    float ob0 = bflo(mh.z) + inv * (bx * m0 + by * m3 + bz * m6) + k0f;
    float ob1 = bfhi(mh.z) + inv * (bx * m1 + by * m4 + bz * m7) + k1f;
    float ob2 = bflo(mh.w) + inv * (bx * m2 + by * m5 + bz * m8) + k2f;
    if (!FINAL) {
        unsigned int dw = (unsigned int)d << 16;
        uint4 o;
        o.x = (unsigned int)f2bf(oa0) | ((unsigned int)f2bf(oa1) << 16);
        o.y = (unsigned int)f2bf(oa2) | dw;
        o.z = (unsigned int)f2bf(ob0) | ((unsigned int)f2bf(ob1) << 16);
        o.w = (unsigned int)f2bf(ob2) | dw;
        outT[(size_t)n * 8 + l] = o;
    } else {
        int b0 = 2 * l, b1 = 2 * l + 1;
        lds[nl * 51 + b0 * 3 + 0] = oa0;
        lds[nl * 51 + b0 * 3 + 1] = oa1;
        lds[nl * 51 + b0 * 3 + 2] = oa2;
        lds[nl * 51 + b1 * 3 + 0] = ob0;
        lds[nl * 51 + b1 * 3 + 1] = ob1;
        lds[nl * 51 + b1 * 3 + 2] = ob2;
        __syncthreads();
        int n2 = t & 15, q = t >> 4;         // q: batch pair 2q,2q+1; n2 fastest
        int gn = blockIdx.x * 16 + n2;
        float* op0 = outP + ((size_t)(2 * q) * N_ATOMS + gn) * 3;
        float* op1 = op0 + (size_t)N_ATOMS * 3;
        op0[0] = lds[n2 * 51 + (2 * q) * 3 + 0];
        op0[1] = lds[n2 * 51 + (2 * q) * 3 + 1];
        op0[2] = lds[n2 * 51 + (2 * q) * 3 + 2];
        op1[0] = lds[n2 * 51 + (2 * q + 1) * 3 + 0];
        op1[1] = lds[n2 * 51 + (2 * q + 1) * 3 + 1];
        op1[2] = lds[n2 * 51 + (2 * q + 1) * 3 + 2];
    }
}

extern "C" void kernel_launch(void* const* d_in, const int* in_sizes, int n_in,
                              void* d_out, int out_size, void* d_ws, size_t ws_size,
                              hipStream_t stream) {
    const float* positions = (const float*)d_in[0];
    const int* bonds = (const int*)d_in[1];
    const float* W_msg = (const float*)d_in[2];
    const float* b_msg = (const float*)d_in[3];
    const float* W_upd = (const float*)d_in[4];
    const float* b_upd = (const float*)d_in[5];
    float* out = (float*)d_out;

    int* wsi = (int*)d_ws;
    int* cnt = wsi + OFF_CNT;
    float* Mc = (float*)(wsi + OFF_MC);
    int* adjF = wsi + OFF_ADJF;
    ushort4* posT = (ushort4*)(wsi + OFF_POST);
    uint4* posT4 = (uint4*)(wsi + OFF_POST);
    uint4* h2T4 = (uint4*)(wsi + OFF_H2T);

    // 1. zero slot counters (driver fill, capture-legal)
    hipMemsetAsync(cnt, 0, N_ATOMS * sizeof(int), stream);
    // 2. LDS-tiled transpose -> posT (bf16) || slot-fill adjacency || Mc
    build_kernel<<<TRANS_BLOCKS + DEG_BLOCKS + 1, 256, 0, stream>>>(
        positions, bonds, W_msg, b_msg, W_upd, cnt, adjF, Mc, posT);
    // 3. iteration 1: posT -> h2T (node-major bf16, deg packed in .w)
    gather_kernel<false><<<NGROUPS, 128, 0, stream>>>(posT4, cnt, adjF, Mc, b_upd, h2T4, nullptr);
    // 4. iteration 2: h2T -> out[B][N][3] f32 (LDS re-transpose)
    gather_kernel<true><<<NGROUPS, 128, 0, stream>>>(h2T4, cnt, adjF, Mc, b_upd, nullptr, out);
}

// Round 15
// 38.812 us; speedup vs baseline: 4.4576x; 1.0205x over previous
//
#include <hip/hip_runtime.h>

#define N_ATOMS 20000
#define BATCH   16
#define N_BONDS 60000
#define NB      (N_ATOMS * BATCH)      // 320000
#define CAP     32                     // max neighbors/node (deg~Poisson(6); P(>=32)~1e-16)

#define TRANS_BLOCKS 1250   // 1250*256 = 320000 = N*B
#define DEG_BLOCKS   235    // ceil(60000/256)
#define NGROUPS      1250   // N_ATOMS/16

// Workspace (int-indexed):
//   cnt[20000] | Mc[12]f(+pad) | adjF[20000*32] | posT[N][16] ushort4 | h2T same
#define OFF_CNT   0
#define OFF_MC    20000
#define OFF_ADJF  20016
#define OFF_POST  (OFF_ADJF + N_ATOMS * CAP)        // *4 bytes %16==0 -> aligned
#define OFF_H2T   (OFF_POST + NB * 2)               // ushort4 = 2 ints each

// f32 <-> bf16 (RNE; data has no NaN/Inf).
__device__ __forceinline__ unsigned short f2bf(float f) {
    unsigned int u = __float_as_uint(f);
    u += 0x7FFFu + ((u >> 16) & 1u);
    return (unsigned short)(u >> 16);
}
__device__ __forceinline__ float bf2f(unsigned short h) {
    return __uint_as_float(((unsigned int)h) << 16);
}

// blocks [0,1250): transpose positions[B][N][3] -> posT[N][16] bf16x4 (b-fastest,
//                  128B-contiguous per node). blocks [1250,1485): slot fill.
// block 1485: Mc = [W_msg @ W_upd ; b_msg @ W_upd].
__global__ void build_kernel(const float* __restrict__ pos, const int* __restrict__ bonds,
                             const float* __restrict__ W_msg, const float* __restrict__ b_msg,
                             const float* __restrict__ W_upd,
                             int* __restrict__ cnt, int* __restrict__ adjF,
                             float* __restrict__ Mc, ushort4* __restrict__ posT) {
    int blk = blockIdx.x;
    if (blk < TRANS_BLOCKS) {
        int t = blk * 256 + threadIdx.x;        // 0..319999
        int b = t & 15, n = t >> 4;
        const float* p = pos + ((size_t)b * N_ATOMS + n) * 3;
        posT[n * 16 + b] = make_ushort4(f2bf(p[0]), f2bf(p[1]), f2bf(p[2]), 0);
    } else if (blk < TRANS_BLOCKS + DEG_BLOCKS) {
        int e = (blk - TRANS_BLOCKS) * 256 + threadIdx.x;
        if (e < N_BONDS) {
            int a0 = bonds[2 * e], a1 = bonds[2 * e + 1];
            int s0 = atomicAdd(&cnt[a0], 1);
            if (s0 < CAP) adjF[a0 * CAP + s0] = a1;
            int s1 = atomicAdd(&cnt[a1], 1);
            if (s1 < CAP) adjF[a1 * CAP + s1] = a0;
        }
    } else {
        int t = threadIdx.x;
        if (t < 12) {
            float s = 0.0f;
            if (t < 9) {
                int i = t / 3, j = t % 3;
                for (int k = 0; k < 128; ++k) s += W_msg[i * 128 + k] * W_upd[k * 3 + j];
            } else {
                int j = t - 9;
                for (int k = 0; k < 128; ++k) s += b_msg[k] * W_upd[k * 3 + j];
            }
            Mc[t] = s;
        }
    }
}

// Node-major fused iteration, bf16 state. 16 lanes/node read one 128B line per
// neighbor. Front-loaded MLP: 2 unconditional int4 adj loads cover d<=8 (84%);
// up to 8 independent predicated gathers in flight. f32 accumulation.
template <bool FINAL>
__global__ __launch_bounds__(256) void gather_kernel(const ushort4* __restrict__ hT,
                                                     const int* __restrict__ cnt,
                                                     const int* __restrict__ adjF,
                                                     const float* __restrict__ Mc,
                                                     const float* __restrict__ b_upd,
                                                     ushort4* __restrict__ outT,
                                                     float* __restrict__ outP) {
    __shared__ float lds[16 * 51];           // stride 51: conflict-free re-transpose
    int t = threadIdx.x;
    int b = t & 15;
    int nl = t >> 4;
    int n = blockIdx.x * 16 + nl;            // 1250*16 = 20000 exactly
    const int4* al4 = (const int4*)(adjF + n * CAP);
    int dc = cnt[n];                         // group-uniform broadcast
    int d = dc > CAP ? CAP : dc;
    int4 ja = al4[0];                        // always in-bounds (CAP=32)
    int4 jb = al4[1];
    ushort4 mh = hT[n * 16 + b];             // issued early, independent
    float sx = 0.0f, sy = 0.0f, sz = 0.0f;
#define ACC(J) { ushort4 v = hT[(size_t)(J) * 16 + b]; \
                 sx += bf2f(v.x); sy += bf2f(v.y); sz += bf2f(v.z); }
    if (0 < d) ACC(ja.x)
    if (1 < d) ACC(ja.y)
    if (2 < d) ACC(ja.z)
    if (3 < d) ACC(ja.w)
    if (4 < d) ACC(jb.x)
    if (5 < d) ACC(jb.y)
    if (6 < d) ACC(jb.z)
    if (7 < d) ACC(jb.w)
    for (int k0 = 8; k0 < d; k0 += 8) {      // rare tail (P(d>8)~15%)
        ja = al4[k0 >> 2];
        jb = al4[(k0 >> 2) + 1];
        if (k0 + 0 < d) ACC(ja.x)
        if (k0 + 1 < d) ACC(ja.y)
        if (k0 + 2 < d) ACC(ja.z)
        if (k0 + 3 < d) ACC(ja.w)
        if (k0 + 4 < d) ACC(jb.x)
        if (k0 + 5 < d) ACC(jb.y)
        if (k0 + 6 < d) ACC(jb.z)
        if (k0 + 7 < d) ACC(jb.w)
    }
#undef ACC
    float mex = bf2f(mh.x), mey = bf2f(mh.y), mez = bf2f(mh.z);
    float inv = d > 0 ? 1.0f / (float)d : 0.0f;
    float flag = d > 0 ? 1.0f : 0.0f;
    float o0 = mex + inv * (sx * Mc[0] + sy * Mc[3] + sz * Mc[6]) + flag * Mc[9]  + b_upd[0];
    float o1 = mey + inv * (sx * Mc[1] + sy * Mc[4] + sz * Mc[7]) + flag * Mc[10] + b_upd[1];
    float o2 = mez + inv * (sx * Mc[2] + sy * Mc[5] + sz * Mc[8]) + flag * Mc[11] + b_upd[2];
    if (!FINAL) {
        outT[n * 16 + b] = make_ushort4(f2bf(o0), f2bf(o1), f2bf(o2), 0);
    } else {
        lds[nl * 51 + b * 3 + 0] = o0;
        lds[nl * 51 + b * 3 + 1] = o1;
        lds[nl * 51 + b * 3 + 2] = o2;
        __syncthreads();
        int b2 = t >> 4, n2 = t & 15;        // remap: n fastest -> coalesced writes
        float* op = outP + ((size_t)b2 * N_ATOMS + (size_t)(blockIdx.x * 16 + n2)) * 3;
        op[0] = lds[n2 * 51 + b2 * 3 + 0];
        op[1] = lds[n2 * 51 + b2 * 3 + 1];
        op[2] = lds[n2 * 51 + b2 * 3 + 2];
    }
}

extern "C" void kernel_launch(void* const* d_in, const int* in_sizes, int n_in,
                              void* d_out, int out_size, void* d_ws, size_t ws_size,
                              hipStream_t stream) {
    const float* positions = (const float*)d_in[0];
    const int* bonds = (const int*)d_in[1];
    const float* W_msg = (const float*)d_in[2];
    const float* b_msg = (const float*)d_in[3];
    const float* W_upd = (const float*)d_in[4];
    const float* b_upd = (const float*)d_in[5];
    float* out = (float*)d_out;

    int* wsi = (int*)d_ws;
    int* cnt = wsi + OFF_CNT;
    float* Mc = (float*)(wsi + OFF_MC);
    int* adjF = wsi + OFF_ADJF;
    ushort4* posT = (ushort4*)(wsi + OFF_POST);
    ushort4* h2T = (ushort4*)(wsi + OFF_H2T);

    // 1. zero slot counters (driver fill, capture-legal)
    hipMemsetAsync(cnt, 0, N_ATOMS * sizeof(int), stream);
    // 2. transpose -> posT (bf16) || slot-fill adjacency || Mc (fused by block range)
    build_kernel<<<TRANS_BLOCKS + DEG_BLOCKS + 1, 256, 0, stream>>>(
        positions, bonds, W_msg, b_msg, W_upd, cnt, adjF, Mc, posT);
    // 3. iteration 1: posT -> h2T (node-major bf16)
    gather_kernel<false><<<NGROUPS, 256, 0, stream>>>(posT, cnt, adjF, Mc, b_upd, h2T, nullptr);
    // 4. iteration 2: h2T -> out[B][N][3] f32 (LDS re-transpose)
    gather_kernel<true><<<NGROUPS, 256, 0, stream>>>(h2T, cnt, adjF, Mc, b_upd, nullptr, out);
}